// Round 7
// baseline (141.815 us; speedup 1.0000x reference)
//
#include <hip/hip_runtime.h>
#include <math.h>

// Problem constants (match reference)
#define BB 4
#define SS 2048
#define EE 16
#define HH 4
#define DK 4
#define KS 8                  // key splits
#define QC 2                  // query chunks
#define NQ (BB*HH*SS)         // 32768 total query rows
#define KLEN (SS/KS)          // 256 keys per split

// q pre-scaled by (1/sqrt(DK)) * log2(e): attn loop is pure exp2 domain.
// No-running-max softmax is safe: |log2 score| <= ~15 worst case -> exp2 sums
// stay far below fp32 overflow; equals reference softmax in exact arithmetic.
#define QSCALE 0.7213475204444817f   // 0.5 * log2(e)

typedef float v2f __attribute__((ext_vector_type(2)));

// ---------------------------------------------------------------------------
// Single fused kernel: proj + flash attention (no running max, packed across
// keys) + "last block of group finishes" epilogue that applies the cross-head
// Wc mix and writes final out. Group = (b, qc): 32 producer blocks
// (4 heads x 8 key-splits). Producer part is identical to R6's verified body.
// ---------------------------------------------------------------------------
__global__ __launch_bounds__(512) void attn_fused(
    const float* __restrict__ x, const float* __restrict__ theta,
    const float* __restrict__ Wk, const float* __restrict__ Wv,
    const float* __restrict__ Wc, float* __restrict__ out,
    float* __restrict__ accp, float* __restrict__ lp,
    unsigned int* __restrict__ cnt)
{
    __shared__ float skx[KLEN], sky[KLEN], skz[KLEN], skw[KLEN];
    __shared__ float svx[KLEN], svy[KLEN], svz[KLEN], svw[KLEN];
    __shared__ int sFinish;

    int tid = threadIdx.x;
    int qc = blockIdx.x;                 // 0..QC-1
    int ks = blockIdx.y;                 // 0..KS-1
    int bh = blockIdx.z;                 // 0..15
    int b = bh >> 2;
    int h = bh & 3;

    // --- K/V for this chunk: threads 0..KLEN-1, one key each, from global x.
    if (tid < KLEN) {
        const float4* xr = reinterpret_cast<const float4*>(
            x + ((size_t)b*SS + (size_t)ks*KLEN + tid) * EE);
        float4 x0 = xr[0], x1 = xr[1], x2 = xr[2], x3 = xr[3];
        float xv[EE] = {x0.x,x0.y,x0.z,x0.w, x1.x,x1.y,x1.z,x1.w,
                        x2.x,x2.y,x2.z,x2.w, x3.x,x3.y,x3.z,x3.w};
        float kd[DK], vd[DK];
        #pragma unroll
        for (int d = 0; d < DK; ++d) {
            float ak = 0.f, av = 0.f;
            #pragma unroll
            for (int e = 0; e < EE; ++e) {
                ak = fmaf(xv[e], Wk[(h*4+d)*EE + e], ak);   // x @ W^T
                av = fmaf(xv[e], Wv[(h*4+d)*EE + e], av);
            }
            kd[d] = ak; vd[d] = av;
        }
        skx[tid] = kd[0]; sky[tid] = kd[1]; skz[tid] = kd[2]; skw[tid] = kd[3];
        svx[tid] = vd[0]; svy[tid] = vd[1]; svz[tid] = vd[2]; svw[tid] = vd[3];
    }

    // --- q for this thread's 2 queries (broadcast-duplicated into v2f).
    float th0 = theta[h*4+0], th1 = theta[h*4+1];
    float th2 = theta[h*4+2], th3 = theta[h*4+3];   // uniform -> SGPR
    int s0 = qc*1024 + tid;          // second query: s0 + 512
    float4 xq0 = *reinterpret_cast<const float4*>(x + ((size_t)b*SS + s0) * EE + h*4);
    float4 xq1 = *reinterpret_cast<const float4*>(x + ((size_t)b*SS + s0 + 512) * EE + h*4);
    float q0x = __cosf(xq0.x + th0) * QSCALE, q0y = __cosf(xq0.y + th1) * QSCALE;
    float q0z = __cosf(xq0.z + th2) * QSCALE, q0w = __cosf(xq0.w + th3) * QSCALE;
    float q1x = __cosf(xq1.x + th0) * QSCALE, q1y = __cosf(xq1.y + th1) * QSCALE;
    float q1z = __cosf(xq1.z + th2) * QSCALE, q1w = __cosf(xq1.w + th3) * QSCALE;
    v2f Q0x = {q0x,q0x}, Q0y = {q0y,q0y}, Q0z = {q0z,q0z}, Q0w = {q0w,q0w};
    v2f Q1x = {q1x,q1x}, Q1y = {q1y,q1y}, Q1z = {q1z,q1z}, Q1w = {q1w,q1w};

    __syncthreads();

    // --- inner loop: 4 keys per iter, packed key-pair math.
    v2f a0x = {}, a0y = {}, a0z = {}, a0w = {};
    v2f a1x = {}, a1y = {}, a1z = {}, a1w = {};
    v2f l0 = {}, l1 = {};
    const float4* kx4 = reinterpret_cast<const float4*>(skx);
    const float4* ky4 = reinterpret_cast<const float4*>(sky);
    const float4* kz4 = reinterpret_cast<const float4*>(skz);
    const float4* kw4 = reinterpret_cast<const float4*>(skw);
    const float4* vx4 = reinterpret_cast<const float4*>(svx);
    const float4* vy4 = reinterpret_cast<const float4*>(svy);
    const float4* vz4 = reinterpret_cast<const float4*>(svz);
    const float4* vw4 = reinterpret_cast<const float4*>(svw);

    #pragma unroll 2
    for (int i = 0; i < KLEN/4; ++i) {
        float4 kx = kx4[i], ky = ky4[i], kz = kz4[i], kw = kw4[i];
        float4 vx = vx4[i], vy = vy4[i], vz = vz4[i], vw = vw4[i];
        v2f kx01 = {kx.x, kx.y}, kx23 = {kx.z, kx.w};
        v2f ky01 = {ky.x, ky.y}, ky23 = {ky.z, ky.w};
        v2f kz01 = {kz.x, kz.y}, kz23 = {kz.z, kz.w};
        v2f kw01 = {kw.x, kw.y}, kw23 = {kw.z, kw.w};
        v2f vx01 = {vx.x, vx.y}, vx23 = {vx.z, vx.w};
        v2f vy01 = {vy.x, vy.y}, vy23 = {vy.z, vy.w};
        v2f vz01 = {vz.x, vz.y}, vz23 = {vz.z, vz.w};
        v2f vw01 = {vw.x, vw.y}, vw23 = {vw.z, vw.w};

        // query 0, key pair 01
        v2f sc = __builtin_elementwise_fma(Q0x, kx01,
                 __builtin_elementwise_fma(Q0y, ky01,
                 __builtin_elementwise_fma(Q0z, kz01, Q0w * kw01)));
        v2f p; p.x = __builtin_amdgcn_exp2f(sc.x); p.y = __builtin_amdgcn_exp2f(sc.y);
        l0 += p;
        a0x = __builtin_elementwise_fma(p, vx01, a0x);
        a0y = __builtin_elementwise_fma(p, vy01, a0y);
        a0z = __builtin_elementwise_fma(p, vz01, a0z);
        a0w = __builtin_elementwise_fma(p, vw01, a0w);
        // query 0, key pair 23
        sc = __builtin_elementwise_fma(Q0x, kx23,
             __builtin_elementwise_fma(Q0y, ky23,
             __builtin_elementwise_fma(Q0z, kz23, Q0w * kw23)));
        p.x = __builtin_amdgcn_exp2f(sc.x); p.y = __builtin_amdgcn_exp2f(sc.y);
        l0 += p;
        a0x = __builtin_elementwise_fma(p, vx23, a0x);
        a0y = __builtin_elementwise_fma(p, vy23, a0y);
        a0z = __builtin_elementwise_fma(p, vz23, a0z);
        a0w = __builtin_elementwise_fma(p, vw23, a0w);
        // query 1, key pair 01
        sc = __builtin_elementwise_fma(Q1x, kx01,
             __builtin_elementwise_fma(Q1y, ky01,
             __builtin_elementwise_fma(Q1z, kz01, Q1w * kw01)));
        p.x = __builtin_amdgcn_exp2f(sc.x); p.y = __builtin_amdgcn_exp2f(sc.y);
        l1 += p;
        a1x = __builtin_elementwise_fma(p, vx01, a1x);
        a1y = __builtin_elementwise_fma(p, vy01, a1y);
        a1z = __builtin_elementwise_fma(p, vz01, a1z);
        a1w = __builtin_elementwise_fma(p, vw01, a1w);
        // query 1, key pair 23
        sc = __builtin_elementwise_fma(Q1x, kx23,
             __builtin_elementwise_fma(Q1y, ky23,
             __builtin_elementwise_fma(Q1z, kz23, Q1w * kw23)));
        p.x = __builtin_amdgcn_exp2f(sc.x); p.y = __builtin_amdgcn_exp2f(sc.y);
        l1 += p;
        a1x = __builtin_elementwise_fma(p, vx23, a1x);
        a1y = __builtin_elementwise_fma(p, vy23, a1y);
        a1z = __builtin_elementwise_fma(p, vz23, a1z);
        a1w = __builtin_elementwise_fma(p, vw23, a1w);
    }

    // --- epilogue: fold key-pair lanes, store partials (lane-consecutive).
    int gq0 = bh*SS + s0;
    *reinterpret_cast<float4*>(accp + ((size_t)ks*NQ + gq0)*4) =
        make_float4(a0x.x + a0x.y, a0y.x + a0y.y, a0z.x + a0z.y, a0w.x + a0w.y);
    lp[(size_t)ks*NQ + gq0] = l0.x + l0.y;
    *reinterpret_cast<float4*>(accp + ((size_t)ks*NQ + gq0 + 512)*4) =
        make_float4(a1x.x + a1x.y, a1y.x + a1y.y, a1z.x + a1z.y, a1w.x + a1w.y);
    lp[(size_t)ks*NQ + gq0 + 512] = l1.x + l1.y;

    // --- "last block of group finishes": group = (b, qc), 32 producers.
    __threadfence();                       // release: partials visible device-wide
    if (tid == 0) {
        unsigned int old = atomicAdd(&cnt[b*QC + qc], 1u);
        sFinish = (old == HH*KS - 1) ? 1 : 0;
    }
    __syncthreads();
    if (!sFinish) return;
    __threadfence();                       // acquire side

    // Finisher: combine partials, normalize, apply Wc for this group's
    // 1024 tokens (2 per thread: s = qc*1024 + tid, + 512).
    #pragma unroll
    for (int j = 0; j < 2; ++j) {
        int s = qc*1024 + tid + j*512;
        int t = b*SS + s;

        float attn[EE];
        #pragma unroll
        for (int hh = 0; hh < HH; ++hh) {
            int gq = (b*HH + hh)*SS + s;
            float ax = 0.f, ay = 0.f, az = 0.f, aw = 0.f, l = 0.f;
            #pragma unroll
            for (int k = 0; k < KS; ++k) {
                float4 a = *reinterpret_cast<const float4*>(accp + ((size_t)k*NQ + gq)*4);
                ax += a.x; ay += a.y; az += a.z; aw += a.w;
                l += lp[(size_t)k*NQ + gq];
            }
            float inv = 1.0f / l;
            attn[hh*4+0] = ax*inv; attn[hh*4+1] = ay*inv;
            attn[hh*4+2] = az*inv; attn[hh*4+3] = aw*inv;
        }

        float4* orow = reinterpret_cast<float4*>(out + (size_t)t * EE);
        #pragma unroll
        for (int e4 = 0; e4 < 4; ++e4) {
            float o[4];
            #pragma unroll
            for (int i = 0; i < 4; ++i) {
                int e = e4*4 + i;
                float acc = 0.f;
                #pragma unroll
                for (int jj = 0; jj < EE; ++jj)
                    acc = fmaf(attn[jj], Wc[e*EE + jj], acc);   // out = attn @ Wc^T
                o[i] = acc;
            }
            orow[e4] = make_float4(o[0], o[1], o[2], o[3]);
        }
    }
}

// ---------------------------------------------------------------------------
extern "C" void kernel_launch(void* const* d_in, const int* in_sizes, int n_in,
                              void* d_out, int out_size, void* d_ws, size_t ws_size,
                              hipStream_t stream)
{
    const float* x     = (const float*)d_in[0];
    const float* theta = (const float*)d_in[1];
    const float* Wk    = (const float*)d_in[2];
    const float* Wv    = (const float*)d_in[3];
    const float* Wc    = (const float*)d_in[4];
    float* out = (float*)d_out;

    // Workspace carve: cnt (8 u32, padded to 64 floats) | accp 4MB | lp 1MB
    float* ws   = (float*)d_ws;
    unsigned int* cnt = (unsigned int*)ws;
    float* accp = ws + 64;                  // KS*NQ*4, 16B-aligned
    float* lp   = accp + (size_t)KS*NQ*4;   // KS*NQ

    hipMemsetAsync(cnt, 0, QC*BB*sizeof(unsigned int), stream);
    attn_fused<<<dim3(QC, KS, BB*HH), 512, 0, stream>>>(
        x, theta, Wk, Wv, Wc, out, accp, lp, cnt);
}

// Round 8
// 82.526 us; speedup vs baseline: 1.7184x; 1.7184x over previous
//
#include <hip/hip_runtime.h>
#include <math.h>

// Problem constants (match reference)
#define BB 4
#define SS 2048
#define EE 16
#define HH 4
#define DK 4
#define KS 8                  // key splits
#define QC 2                  // query chunks
#define NQ (BB*HH*SS)         // 32768 total query rows
#define KLEN (SS/KS)          // 256 keys per split

// q pre-scaled by (1/sqrt(DK)) * log2(e): attn loop is pure exp2 domain.
// No-running-max softmax is safe: |log2 score| <= ~15 worst case -> exp2 sums
// stay far below fp32 overflow; equals reference softmax in exact arithmetic.
#define QSCALE 0.7213475204444817f   // 0.5 * log2(e)

typedef float v2f __attribute__((ext_vector_type(2)));

// ---------------------------------------------------------------------------
// Kernel 1: fused proj + flash attention (no running max), packed across KEYS.
// R6-verified body. NOTE (R7 lesson): do NOT fuse the combine via
// __threadfence+atomic "last block finishes" — device-scope release/acquire
// on non-coherent per-XCD L2s cost ~80 us across 256 blocks (10x the kernel).
// ---------------------------------------------------------------------------
__global__ __launch_bounds__(512) void attn_kernel(
    const float* __restrict__ x, const float* __restrict__ theta,
    const float* __restrict__ Wk, const float* __restrict__ Wv,
    float* __restrict__ accp, float* __restrict__ lp)
{
    __shared__ float skx[KLEN], sky[KLEN], skz[KLEN], skw[KLEN];
    __shared__ float svx[KLEN], svy[KLEN], svz[KLEN], svw[KLEN];

    int tid = threadIdx.x;
    int qc = blockIdx.x;                 // 0..QC-1
    int ks = blockIdx.y;                 // 0..KS-1
    int bh = blockIdx.z;                 // 0..15
    int b = bh >> 2;
    int h = bh & 3;

    // --- K/V for this chunk: threads 0..KLEN-1, one key each, from global x.
    if (tid < KLEN) {
        const float4* xr = reinterpret_cast<const float4*>(
            x + ((size_t)b*SS + (size_t)ks*KLEN + tid) * EE);
        float4 x0 = xr[0], x1 = xr[1], x2 = xr[2], x3 = xr[3];
        float xv[EE] = {x0.x,x0.y,x0.z,x0.w, x1.x,x1.y,x1.z,x1.w,
                        x2.x,x2.y,x2.z,x2.w, x3.x,x3.y,x3.z,x3.w};
        float kd[DK], vd[DK];
        #pragma unroll
        for (int d = 0; d < DK; ++d) {
            float ak = 0.f, av = 0.f;
            #pragma unroll
            for (int e = 0; e < EE; ++e) {
                ak = fmaf(xv[e], Wk[(h*4+d)*EE + e], ak);   // x @ W^T
                av = fmaf(xv[e], Wv[(h*4+d)*EE + e], av);
            }
            kd[d] = ak; vd[d] = av;
        }
        skx[tid] = kd[0]; sky[tid] = kd[1]; skz[tid] = kd[2]; skw[tid] = kd[3];
        svx[tid] = vd[0]; svy[tid] = vd[1]; svz[tid] = vd[2]; svw[tid] = vd[3];
    }

    // --- q for this thread's 2 queries (broadcast-duplicated into v2f).
    float th0 = theta[h*4+0], th1 = theta[h*4+1];
    float th2 = theta[h*4+2], th3 = theta[h*4+3];   // uniform -> SGPR
    int s0 = qc*1024 + tid;          // second query: s0 + 512
    float4 xq0 = *reinterpret_cast<const float4*>(x + ((size_t)b*SS + s0) * EE + h*4);
    float4 xq1 = *reinterpret_cast<const float4*>(x + ((size_t)b*SS + s0 + 512) * EE + h*4);
    float q0x = __cosf(xq0.x + th0) * QSCALE, q0y = __cosf(xq0.y + th1) * QSCALE;
    float q0z = __cosf(xq0.z + th2) * QSCALE, q0w = __cosf(xq0.w + th3) * QSCALE;
    float q1x = __cosf(xq1.x + th0) * QSCALE, q1y = __cosf(xq1.y + th1) * QSCALE;
    float q1z = __cosf(xq1.z + th2) * QSCALE, q1w = __cosf(xq1.w + th3) * QSCALE;
    v2f Q0x = {q0x,q0x}, Q0y = {q0y,q0y}, Q0z = {q0z,q0z}, Q0w = {q0w,q0w};
    v2f Q1x = {q1x,q1x}, Q1y = {q1y,q1y}, Q1z = {q1z,q1z}, Q1w = {q1w,q1w};

    __syncthreads();

    // --- inner loop: 4 keys per iter, packed key-pair math (v_pk_fma_f32).
    v2f a0x = {}, a0y = {}, a0z = {}, a0w = {};
    v2f a1x = {}, a1y = {}, a1z = {}, a1w = {};
    v2f l0 = {}, l1 = {};
    const float4* kx4 = reinterpret_cast<const float4*>(skx);
    const float4* ky4 = reinterpret_cast<const float4*>(sky);
    const float4* kz4 = reinterpret_cast<const float4*>(skz);
    const float4* kw4 = reinterpret_cast<const float4*>(skw);
    const float4* vx4 = reinterpret_cast<const float4*>(svx);
    const float4* vy4 = reinterpret_cast<const float4*>(svy);
    const float4* vz4 = reinterpret_cast<const float4*>(svz);
    const float4* vw4 = reinterpret_cast<const float4*>(svw);

    #pragma unroll 2
    for (int i = 0; i < KLEN/4; ++i) {
        float4 kx = kx4[i], ky = ky4[i], kz = kz4[i], kw = kw4[i];
        float4 vx = vx4[i], vy = vy4[i], vz = vz4[i], vw = vw4[i];
        v2f kx01 = {kx.x, kx.y}, kx23 = {kx.z, kx.w};
        v2f ky01 = {ky.x, ky.y}, ky23 = {ky.z, ky.w};
        v2f kz01 = {kz.x, kz.y}, kz23 = {kz.z, kz.w};
        v2f kw01 = {kw.x, kw.y}, kw23 = {kw.z, kw.w};
        v2f vx01 = {vx.x, vx.y}, vx23 = {vx.z, vx.w};
        v2f vy01 = {vy.x, vy.y}, vy23 = {vy.z, vy.w};
        v2f vz01 = {vz.x, vz.y}, vz23 = {vz.z, vz.w};
        v2f vw01 = {vw.x, vw.y}, vw23 = {vw.z, vw.w};

        // query 0, key pair 01
        v2f sc = __builtin_elementwise_fma(Q0x, kx01,
                 __builtin_elementwise_fma(Q0y, ky01,
                 __builtin_elementwise_fma(Q0z, kz01, Q0w * kw01)));
        v2f p; p.x = __builtin_amdgcn_exp2f(sc.x); p.y = __builtin_amdgcn_exp2f(sc.y);
        l0 += p;
        a0x = __builtin_elementwise_fma(p, vx01, a0x);
        a0y = __builtin_elementwise_fma(p, vy01, a0y);
        a0z = __builtin_elementwise_fma(p, vz01, a0z);
        a0w = __builtin_elementwise_fma(p, vw01, a0w);
        // query 0, key pair 23
        sc = __builtin_elementwise_fma(Q0x, kx23,
             __builtin_elementwise_fma(Q0y, ky23,
             __builtin_elementwise_fma(Q0z, kz23, Q0w * kw23)));
        p.x = __builtin_amdgcn_exp2f(sc.x); p.y = __builtin_amdgcn_exp2f(sc.y);
        l0 += p;
        a0x = __builtin_elementwise_fma(p, vx23, a0x);
        a0y = __builtin_elementwise_fma(p, vy23, a0y);
        a0z = __builtin_elementwise_fma(p, vz23, a0z);
        a0w = __builtin_elementwise_fma(p, vw23, a0w);
        // query 1, key pair 01
        sc = __builtin_elementwise_fma(Q1x, kx01,
             __builtin_elementwise_fma(Q1y, ky01,
             __builtin_elementwise_fma(Q1z, kz01, Q1w * kw01)));
        p.x = __builtin_amdgcn_exp2f(sc.x); p.y = __builtin_amdgcn_exp2f(sc.y);
        l1 += p;
        a1x = __builtin_elementwise_fma(p, vx01, a1x);
        a1y = __builtin_elementwise_fma(p, vy01, a1y);
        a1z = __builtin_elementwise_fma(p, vz01, a1z);
        a1w = __builtin_elementwise_fma(p, vw01, a1w);
        // query 1, key pair 23
        sc = __builtin_elementwise_fma(Q1x, kx23,
             __builtin_elementwise_fma(Q1y, ky23,
             __builtin_elementwise_fma(Q1z, kz23, Q1w * kw23)));
        p.x = __builtin_amdgcn_exp2f(sc.x); p.y = __builtin_amdgcn_exp2f(sc.y);
        l1 += p;
        a1x = __builtin_elementwise_fma(p, vx23, a1x);
        a1y = __builtin_elementwise_fma(p, vy23, a1y);
        a1z = __builtin_elementwise_fma(p, vz23, a1z);
        a1w = __builtin_elementwise_fma(p, vw23, a1w);
    }

    // --- epilogue: fold key-pair lanes, store partials (lane-consecutive).
    int gq0 = bh*SS + s0;
    *reinterpret_cast<float4*>(accp + ((size_t)ks*NQ + gq0)*4) =
        make_float4(a0x.x + a0x.y, a0y.x + a0y.y, a0z.x + a0z.y, a0w.x + a0w.y);
    lp[(size_t)ks*NQ + gq0] = l0.x + l0.y;
    *reinterpret_cast<float4*>(accp + ((size_t)ks*NQ + gq0 + 512)*4) =
        make_float4(a1x.x + a1x.y, a1y.x + a1y.y, a1z.x + a1z.y, a1w.x + a1w.y);
    lp[(size_t)ks*NQ + gq0 + 512] = l1.x + l1.y;
}

// ---------------------------------------------------------------------------
// Kernel 2 (v2): combine partials + Wc. One thread per (token, head): 4x the
// TLP of the per-token version; all 8 float4 + 8 scalar partial loads are
// independent (single waitcnt). The 4 heads of a token exchange normalized
// attn quarter-rows via LDS (stride 16 floats -> 2-way bank alias = free),
// then each thread computes 4 of the 16 Wc outputs.
// Block: 256 threads = 64 tokens x 4 heads. Grid: 8192/64 = 128 blocks.
// ---------------------------------------------------------------------------
__global__ __launch_bounds__(256) void out_kernel(
    const float* __restrict__ accp, const float* __restrict__ lp,
    const float* __restrict__ Wc, float* __restrict__ out)
{
    __shared__ float sattn[64 * EE];          // 4 KB

    int tid = threadIdx.x;
    int tok = tid & 63;                       // token within block
    int grp = tid >> 6;                       // head (phase 1) / out-quarter (phase 2)
    int t = blockIdx.x * 64 + tok;            // global token 0..8191
    int b = t >> 11;
    int s = t & (SS - 1);

    // --- phase 1: reduce key-split partials for head `grp` of token t.
    int gq = (b*HH + grp)*SS + s;
    float ax = 0.f, ay = 0.f, az = 0.f, aw = 0.f, l = 0.f;
    #pragma unroll
    for (int k = 0; k < KS; ++k) {
        float4 a = *reinterpret_cast<const float4*>(accp + ((size_t)k*NQ + gq)*4);
        ax += a.x; ay += a.y; az += a.z; aw += a.w;
        l += lp[(size_t)k*NQ + gq];
    }
    float inv = 1.0f / l;
    *reinterpret_cast<float4*>(sattn + tok*EE + grp*4) =
        make_float4(ax*inv, ay*inv, az*inv, aw*inv);

    __syncthreads();

    // --- phase 2: outputs e = grp*4 .. grp*4+3 for token t.
    float at[EE];
    #pragma unroll
    for (int j = 0; j < EE; j += 4) {
        float4 v = *reinterpret_cast<const float4*>(sattn + tok*EE + j);
        at[j] = v.x; at[j+1] = v.y; at[j+2] = v.z; at[j+3] = v.w;
    }
    float o[4];
    #pragma unroll
    for (int i = 0; i < 4; ++i) {
        int e = grp*4 + i;
        float acc = 0.f;
        #pragma unroll
        for (int j = 0; j < EE; ++j)
            acc = fmaf(at[j], Wc[e*EE + j], acc);     // out = attn @ Wc^T
        o[i] = acc;
    }
    *reinterpret_cast<float4*>(out + (size_t)t*EE + grp*4) =
        make_float4(o[0], o[1], o[2], o[3]);
}

// ---------------------------------------------------------------------------
extern "C" void kernel_launch(void* const* d_in, const int* in_sizes, int n_in,
                              void* d_out, int out_size, void* d_ws, size_t ws_size,
                              hipStream_t stream)
{
    const float* x     = (const float*)d_in[0];
    const float* theta = (const float*)d_in[1];
    const float* Wk    = (const float*)d_in[2];
    const float* Wv    = (const float*)d_in[3];
    const float* Wc    = (const float*)d_in[4];
    float* out = (float*)d_out;

    // Workspace carve (floats): accp 4MB | lp 1MB
    float* ws   = (float*)d_ws;
    float* accp = ws;                       // KS*NQ*4
    float* lp   = accp + (size_t)KS*NQ*4;   // KS*NQ

    attn_kernel<<<dim3(QC, KS, BB*HH), 512, 0, stream>>>(x, theta, Wk, Wv, accp, lp);
    out_kernel<<<dim3((BB*SS)/64), 256, 0, stream>>>(accp, lp, Wc, out);
}